// Round 3
// baseline (411.898 us; speedup 1.0000x reference)
//
#include <hip/hip_runtime.h>
#include <hip/hip_bf16.h>
#include <math.h>

#define BB 64
#define TT 4096
#define II 128
#define HH 256
#define LC 64            // chunk length
#define NC 64            // chunks = TT/LC

typedef __attribute__((ext_vector_type(8))) short short8;   // 8 bf16 (4 VGPRs)
typedef __attribute__((ext_vector_type(4))) float f32x4;

__device__ inline ushort f2b(float f) {
    __hip_bfloat16 h = __float2bfloat16(f);
    return *reinterpret_cast<ushort*>(&h);
}
__device__ inline float b2f(ushort u) {
    union { unsigned u; float f; } c; c.u = ((unsigned)u) << 16; return c.f;
}

// ---------------- K0: tables ----------------
// grid 128 x 256 (idx over 32768)
__global__ __launch_bounds__(256) void k0_tables(
    const float* __restrict__ Wd, const float* __restrict__ bd,
    const float* __restrict__ Wo, const float* __restrict__ tau,
    ushort* __restrict__ Wdb, ushort* __restrict__ Vt,
    float* __restrict__ ApowT, float* __restrict__ alphas,
    float* __restrict__ mb, float* __restrict__ ybias)
{
    int idx = blockIdx.x * 256 + threadIdx.x;
    Wdb[idx] = f2b(Wd[idx]);                     // Wd -> bf16, [h][i]
    if (idx < 16384) {
        int d = idx >> 8, h = idx & 255;         // d=k in 0..63, h in 0..255
        float a = 1.0f / (1.0f + expf(-tau[h]));
        float l2a = log2f(a);
        Vt[idx]    = f2b(Wo[h] * (1.0f - a) * exp2f((float)d * l2a));  // Vt[d][h]
        ApowT[idx] = exp2f((float)(d + 1) * l2a);                      // ApowT[k][h]=a^(k+1)
    }
    if (idx < HH) {
        float a = 1.0f / (1.0f + expf(-tau[idx]));
        alphas[idx] = a;
        mb[idx] = bd[idx] * (1.0f - exp2f(64.0f * log2f(a)));
    }
    if (idx < LC) {
        float s = 0.0f;
        for (int h = 0; h < HH; ++h) {
            float a = 1.0f / (1.0f + expf(-tau[h]));
            s += Wo[h] * bd[h] * (1.0f - exp2f((float)(idx + 1) * log2f(a)));
        }
        ybias[idx] = s;
    }
}

// ---------------- K1: fused MFMA GEMM + scan, L=64 ----------------
// grid = BB*NC = 4096 blocks, 256 threads (4 waves)
__global__ __launch_bounds__(256, 4) void k1_fused(
    const float* __restrict__ x, const ushort* __restrict__ Wdb,
    const ushort* __restrict__ Vt, const float* __restrict__ alphas,
    const float* __restrict__ mb, const float* __restrict__ ApowT,
    float* __restrict__ ypart, float* __restrict__ Mstate)
{
    __shared__ __align__(16) ushort curS[64 * 136];   // 17408 B, current h-half of cur
    __shared__ __align__(16) float  Ps[64 * 66];      // 16896 B, P matrix f32
    __shared__ float mpart[2 * 128];
    __shared__ float psum[64];

    const int b = blockIdx.x >> 6, tc = blockIdx.x & 63;
    const int tid = threadIdx.x;
    const int lane = tid & 63, w = tid >> 6;
    const int l15 = lane & 15, quad = lane >> 4;
    const int t0 = tc * LC;
    const int hl = tid & 127, sh = tid >> 7;

    // ---- preload A fragments straight from global (thread row t = t0+w*16+l15) ----
    short8 afr[4];
    {
        const float* xr = x + ((size_t)b * TT + t0 + w * 16 + l15) * II + quad * 8;
#pragma unroll
        for (int kt = 0; kt < 4; ++kt) {
            float4 xa = *reinterpret_cast<const float4*>(xr + kt * 32);
            float4 xb = *reinterpret_cast<const float4*>(xr + kt * 32 + 4);
            ushort tmp[8];
            tmp[0] = f2b(xa.x); tmp[1] = f2b(xa.y); tmp[2] = f2b(xa.z); tmp[3] = f2b(xa.w);
            tmp[4] = f2b(xb.x); tmp[5] = f2b(xb.y); tmp[6] = f2b(xb.z); tmp[7] = f2b(xb.w);
            afr[kt] = *reinterpret_cast<short8*>(tmp);
        }
    }

    f32x4 acc2[4];
#pragma unroll
    for (int nt = 0; nt < 4; ++nt) acc2[nt] = (f32x4){0.f, 0.f, 0.f, 0.f};
    float Mhi[2] = {0.f, 0.f};

#pragma unroll 1
    for (int hh = 0; hh < 2; ++hh) {
        // ---- MFMA1: this wave's 16 t-rows x 128 h (half) x 128 k ----
        f32x4 acc1[8];
#pragma unroll
        for (int nt = 0; nt < 8; ++nt) acc1[nt] = (f32x4){0.f, 0.f, 0.f, 0.f};
#pragma unroll
        for (int kt = 0; kt < 4; ++kt) {
#pragma unroll
            for (int nt = 0; nt < 8; ++nt) {
                short8 bf = *reinterpret_cast<const short8*>(
                    &Wdb[(size_t)(hh * 128 + nt * 16 + l15) * II + kt * 32 + quad * 8]);
                acc1[nt] = __builtin_amdgcn_mfma_f32_16x16x32_bf16(afr[kt], bf, acc1[nt], 0, 0, 0);
            }
        }
        __syncthreads();   // prev half's curS consumers done
        // ---- write cur half to LDS: rows w*16+quad*4+r, col nt*16+l15 ----
#pragma unroll
        for (int nt = 0; nt < 8; ++nt)
#pragma unroll
            for (int r = 0; r < 4; ++r)
                curS[(w * 16 + quad * 4 + r) * 136 + nt * 16 + l15] = f2b(acc1[nt][r]);
        __syncthreads();   // cur visible
        // ---- scan partial: 2 threads per h, 32-step chains ----
        {
            int h = hh * 128 + hl;
            float a = alphas[h], oma = 1.0f - a;
            float M = 0.0f;
            int sb = sh * 32;
#pragma unroll 8
            for (int s = 0; s < 32; ++s)
                M = fmaf(a, M, oma * b2f(curS[(sb + s) * 136 + hl]));
            if (sh == 0) mpart[hh * 128 + hl] = M;
            else         Mhi[hh] = M;
        }
        // ---- MFMA2: P[s in w*16..+16][d 0..63] += cur @ Vt^T over this h-half ----
#pragma unroll
        for (int kk = 0; kk < 4; ++kk) {
            short8 a2 = *reinterpret_cast<const short8*>(
                &curS[(w * 16 + l15) * 136 + kk * 32 + quad * 8]);
#pragma unroll
            for (int nt = 0; nt < 4; ++nt) {
                short8 b2v = *reinterpret_cast<const short8*>(
                    &Vt[(size_t)(nt * 16 + l15) * 256 + hh * 128 + kk * 32 + quad * 8]);
                acc2[nt] = __builtin_amdgcn_mfma_f32_16x16x32_bf16(a2, b2v, acc2[nt], 0, 0, 0);
            }
        }
    }

    // ---- P -> LDS (f32) ----
#pragma unroll
    for (int nt = 0; nt < 4; ++nt)
#pragma unroll
        for (int r = 0; r < 4; ++r)
            Ps[(w * 16 + quad * 4 + r) * 66 + nt * 16 + l15] = acc2[nt][r];
    __syncthreads();   // Ps + mpart visible; all curS reads done

    // ---- Mstate write (waves 2,3) runs concurrently with antidiag (waves 0,1) ----
    if (sh == 1) {
#pragma unroll
        for (int hh = 0; hh < 2; ++hh) {
            int h = hh * 128 + hl;
            float Mfull = Mhi[hh] + ApowT[31 * 256 + h] * mpart[hh * 128 + hl] + mb[h];
            Mstate[((size_t)b * NC + tc) * HH + h] = Mfull;
        }
    }
    float part = 0.0f;
    if (w < 2) {
        int k = lane;
#pragma unroll 8
        for (int si = 0; si < 32; ++si) {
            int s = w * 32 + si;
            int d = k - s;
            float v = Ps[s * 66 + (d < 0 ? 0 : d)];
            part += (d >= 0) ? v : 0.0f;
        }
        if (w == 1) psum[k] = part;
    }
    __syncthreads();
    if (w == 0)
        ypart[(size_t)b * TT + t0 + lane] = part + psum[lane];
}

// ---------------- K2: chunk-level state chain (in-place Mlocal -> Minit) ----------------
// grid = BB*HH/256 = 64 blocks
__global__ __launch_bounds__(256) void k2_chain(
    float* __restrict__ Mstate, const float* __restrict__ ApowT)
{
    int idx = blockIdx.x * 256 + threadIdx.x;   // over BB*HH
    int b = idx >> 8, h = idx & 255;
    float aL = ApowT[63 * 256 + h];             // a^64
    float M = 0.0f;
#pragma unroll 4
    for (int c = 0; c < NC; ++c) {
        size_t o = ((size_t)b * NC + c) * HH + h;
        float prev = Mstate[o];
        Mstate[o] = M;                          // Minit for chunk c
        M = fmaf(aL, M, prev);
    }
}

// ---------------- K3: fixup + bias + sigmoid ----------------
// grid = BB*NC/4 = 1024 blocks x 256 threads (4 chunks/block)
__global__ __launch_bounds__(256) void k3_out(
    const float* __restrict__ ypart, const float* __restrict__ Mstate,
    const float* __restrict__ ApowT, const float* __restrict__ Wo,
    const float* __restrict__ bo, const float* __restrict__ ybias,
    float* __restrict__ out)
{
    __shared__ __align__(16) float wc[4 * 256];
    const int blk = blockIdx.x;
    const int b = blk >> 4, cg = blk & 15;
    const int tid = threadIdx.x;
#pragma unroll
    for (int r = 0; r < 4; ++r)
        wc[r * 256 + tid] = Wo[tid] * Mstate[((size_t)b * NC + cg * 4 + r) * HH + tid];
    __syncthreads();
    const int c4 = tid >> 6, k = tid & 63;
    const float* wcp = &wc[c4 * 256];
    const float* ap  = &ApowT[k * 256];
    float corr = 0.0f;
#pragma unroll 4
    for (int h4 = 0; h4 < 64; ++h4) {
        float4 wv = *reinterpret_cast<const float4*>(&wcp[h4 * 4]);
        float4 av = *reinterpret_cast<const float4*>(&ap[h4 * 4]);
        corr += wv.x * av.x + wv.y * av.y + wv.z * av.z + wv.w * av.w;
    }
    size_t t = (size_t)b * TT + (size_t)(cg * 4 + c4) * LC + k;
    float z = ypart[t] + corr + ybias[k] + bo[0];
    out[t] = 1.0f / (1.0f + expf(-z));
}

extern "C" void kernel_launch(void* const* d_in, const int* in_sizes, int n_in,
                              void* d_out, int out_size, void* d_ws, size_t ws_size,
                              hipStream_t stream) {
    const float* x   = (const float*)d_in[0];
    const float* Wd  = (const float*)d_in[1];
    const float* bd  = (const float*)d_in[2];
    const float* Wo  = (const float*)d_in[3];
    const float* bo  = (const float*)d_in[4];
    const float* tau = (const float*)d_in[5];
    float* out = (float*)d_out;

    float* ws = (float*)d_ws;
    float*  ypart  = ws;                          // 262144
    float*  Mstate = ws + 262144;                 // 1048576 (Mlocal -> Minit in place)
    float*  ApowT  = ws + 1310720;                // 16384  ApowT[k][h] = a_h^(k+1)
    float*  alphas = ws + 1327104;                // 256
    float*  mb     = ws + 1327360;                // 256
    float*  ybias  = ws + 1327616;                // 64
    ushort* Wdb    = (ushort*)(ws + 1327680);     // 32768 bf16
    ushort* Vt     = (ushort*)(ws + 1344064);     // 16384 bf16  Vt[d][h]

    k0_tables<<<128, 256, 0, stream>>>(Wd, bd, Wo, tau, Wdb, Vt, ApowT, alphas, mb, ybias);
    k1_fused<<<BB * NC, 256, 0, stream>>>(x, Wdb, Vt, alphas, mb, ApowT, ypart, Mstate);
    k2_chain<<<BB * HH / 256, 256, 0, stream>>>(Mstate, ApowT);
    k3_out<<<BB * NC / 4, 256, 0, stream>>>(ypart, Mstate, ApowT, Wo, bo, ybias, out);
}

// Round 4
// 307.514 us; speedup vs baseline: 1.3394x; 1.3394x over previous
//
#include <hip/hip_runtime.h>
#include <hip/hip_bf16.h>
#include <math.h>

#define BB 64
#define TT 4096
#define II 128
#define HH 256
#define LC 128           // chunk length
#define NC 32            // chunks = TT/LC

typedef __attribute__((ext_vector_type(8))) short short8;   // 8 bf16
typedef __attribute__((ext_vector_type(4))) float f32x4;

__device__ inline ushort f2b(float f) {
    __hip_bfloat16 h = __float2bfloat16(f);
    return *reinterpret_cast<ushort*>(&h);
}
__device__ inline float b2f(ushort u) {
    union { unsigned u; float f; } c; c.u = ((unsigned)u) << 16; return c.f;
}

// ---------------- K0: tables ----------------
// grid 128 x 256 (idx over 32768)
__global__ __launch_bounds__(256) void k0_tables(
    const float* __restrict__ Wd, const float* __restrict__ bd,
    const float* __restrict__ Wo, const float* __restrict__ tau,
    ushort* __restrict__ Wdb, ushort* __restrict__ Vt,
    float* __restrict__ ApowT, float* __restrict__ alphas,
    float* __restrict__ mb, float* __restrict__ ybias)
{
    int idx = blockIdx.x * 256 + threadIdx.x;
    Wdb[idx] = f2b(Wd[idx]);                     // [h][i] bf16
    {
        int d = idx >> 8, h = idx & 255;         // d/k in 0..127, h in 0..255
        float a = 1.0f / (1.0f + expf(-tau[h]));
        float l2a = log2f(a);
        Vt[idx]    = f2b(Wo[h] * (1.0f - a) * exp2f((float)d * l2a));  // Vt[d][h]
        ApowT[idx] = exp2f((float)(d + 1) * l2a);                      // ApowT[k][h]=a^(k+1)
    }
    if (idx < HH) {
        float a = 1.0f / (1.0f + expf(-tau[idx]));
        alphas[idx] = a;
        mb[idx] = bd[idx] * (1.0f - exp2f(128.0f * log2f(a)));
    }
    if (idx < LC) {
        float s = 0.0f;
        for (int h = 0; h < HH; ++h) {
            float a = 1.0f / (1.0f + expf(-tau[h]));
            s += Wo[h] * bd[h] * (1.0f - exp2f((float)(idx + 1) * log2f(a)));
        }
        ybias[idx] = s;
    }
}

// ---------------- K1: fused MFMA GEMM + scan-as-GEMM, L=128, 8 waves ----------------
// grid = BB*NC = 2048 blocks, 512 threads
// LDS: region R [0,67584): As(128x132 u16) -> curS(128x264 u16) -> Ps(128x132 f32)
//      mp   [67584, +2048): 2x256 f32 scan partials
//      psum [69632, +2048): 4x128 f32 antidiag partials
__global__ __launch_bounds__(512, 4) void k1_fused(
    const float* __restrict__ x, const ushort* __restrict__ Wdb,
    const ushort* __restrict__ Vt, const float* __restrict__ alphas,
    const float* __restrict__ mb, const float* __restrict__ ApowT,
    float* __restrict__ ypart, float* __restrict__ Mstate)
{
    __shared__ __align__(16) char smem[71680];
    ushort* As   = reinterpret_cast<ushort*>(smem);           // stride 132
    ushort* curS = reinterpret_cast<ushort*>(smem);           // stride 264
    float*  Ps   = reinterpret_cast<float*>(smem);            // stride 132
    float*  mp   = reinterpret_cast<float*>(smem + 67584);
    float*  psum = reinterpret_cast<float*>(smem + 69632);

    const int b = blockIdx.x >> 5, tc = blockIdx.x & 31;
    const int tid = threadIdx.x;
    const int lane = tid & 63, w = tid >> 6;         // 8 waves
    const int l15 = lane & 15, quad = lane >> 4;
    const int t0 = tc * LC;

    // ---- stage x tile (128t x 128i f32) -> bf16 As[t][i], coalesced ----
    {
        const float4* xg = reinterpret_cast<const float4*>(x + ((size_t)b * TT + t0) * II);
#pragma unroll
        for (int it = 0; it < 8; ++it) {
            int idx = it * 512 + tid;               // 4096 float4
            int t = idx >> 5, i4 = idx & 31;
            float4 v = xg[idx];
            ushort4 u;
            u.x = f2b(v.x); u.y = f2b(v.y); u.z = f2b(v.z); u.w = f2b(v.w);
            *reinterpret_cast<ushort4*>(&As[t * 132 + i4 * 4]) = u;
        }
    }
    __syncthreads();   // B0: As visible

    // ---- MFMA1: wave w -> h in [32w, 32w+32), all 128 t ----
    f32x4 acc1[2][8];
#pragma unroll
    for (int nt = 0; nt < 2; ++nt)
#pragma unroll
        for (int mt = 0; mt < 8; ++mt) acc1[nt][mt] = (f32x4){0.f,0.f,0.f,0.f};
#pragma unroll
    for (int kt = 0; kt < 4; ++kt) {
        short8 bf0 = *reinterpret_cast<const short8*>(
            &Wdb[(size_t)(32 * w + l15) * II + kt * 32 + quad * 8]);
        short8 bf1 = *reinterpret_cast<const short8*>(
            &Wdb[(size_t)(32 * w + 16 + l15) * II + kt * 32 + quad * 8]);
#pragma unroll
        for (int mt = 0; mt < 8; ++mt) {
            short8 af = *reinterpret_cast<const short8*>(
                &As[(mt * 16 + l15) * 132 + kt * 32 + quad * 8]);
            acc1[0][mt] = __builtin_amdgcn_mfma_f32_16x16x32_bf16(af, bf0, acc1[0][mt], 0, 0, 0);
            acc1[1][mt] = __builtin_amdgcn_mfma_f32_16x16x32_bf16(af, bf1, acc1[1][mt], 0, 0, 0);
        }
    }
    __syncthreads();   // B1: all As reads done (curS aliases As)

    // ---- write cur to LDS: curS[t][h], stride 264 ----
#pragma unroll
    for (int nt = 0; nt < 2; ++nt)
#pragma unroll
        for (int mt = 0; mt < 8; ++mt)
#pragma unroll
            for (int r = 0; r < 4; ++r)
                curS[(mt * 16 + quad * 4 + r) * 264 + 32 * w + nt * 16 + l15] =
                    f2b(acc1[nt][mt][r]);
    __syncthreads();   // B2: curS visible

    // ---- scan partials: thread (h, half), 64-step chains ----
    {
        int h = tid & 255, half = tid >> 8;
        float a = alphas[h], oma = 1.0f - a;
        float M = 0.0f;
        int sb = half * 64;
#pragma unroll 8
        for (int i = 0; i < 64; ++i)
            M = fmaf(a, M, oma * b2f(curS[(sb + i) * 264 + h]));
        mp[half * 256 + h] = M;
    }

    // ---- MFMA2: wave w -> d in [16w, 16w+16), all 128 s, K=256 h ----
    f32x4 acc2[8];
#pragma unroll
    for (int mt = 0; mt < 8; ++mt) acc2[mt] = (f32x4){0.f,0.f,0.f,0.f};
#pragma unroll
    for (int kk = 0; kk < 8; ++kk) {
        short8 b2 = *reinterpret_cast<const short8*>(
            &Vt[(size_t)(16 * w + l15) * HH + kk * 32 + quad * 8]);
#pragma unroll
        for (int mt = 0; mt < 8; ++mt) {
            short8 a2 = *reinterpret_cast<const short8*>(
                &curS[(mt * 16 + l15) * 264 + kk * 32 + quad * 8]);
            acc2[mt] = __builtin_amdgcn_mfma_f32_16x16x32_bf16(a2, b2, acc2[mt], 0, 0, 0);
        }
    }
    __syncthreads();   // B3: curS reads + mp writes done (Ps aliases curS)

    // ---- Ps write (f32) + Mstate write ----
#pragma unroll
    for (int mt = 0; mt < 8; ++mt)
#pragma unroll
        for (int r = 0; r < 4; ++r)
            Ps[(mt * 16 + quad * 4 + r) * 132 + 16 * w + l15] = acc2[mt][r];
    if (tid < HH) {
        int h = tid;
        float Mfull = ApowT[63 * 256 + h] * mp[h] + mp[256 + h] + mb[h];
        Mstate[((size_t)b * NC + tc) * HH + h] = Mfull;
    }
    __syncthreads();   // B4: Ps visible

    // ---- anti-diagonal: y[k] = sum_{s<=k} Ps[s][k-s], 4-way split over s ----
    float part = 0.0f;
    {
        int k = tid & 127, g = tid >> 7;
        int sb = g * 32;
#pragma unroll 8
        for (int i = 0; i < 32; ++i) {
            int s = sb + i;
            int d = k - s;
            float v = Ps[s * 132 + (d < 0 ? 0 : d)];
            part += (d >= 0) ? v : 0.0f;
        }
        if (g > 0) psum[g * 128 + k] = part;
    }
    __syncthreads();   // B5
    if (tid < 128) {
        int k = tid;
        float y = part + psum[128 + k] + psum[256 + k] + psum[384 + k];
        ypart[(size_t)b * TT + t0 + k] = y;
    }
}

// ---------------- K2: chunk-level state chain (in-place Mlocal -> Minit) ----------------
// grid = 64 blocks x 256
__global__ __launch_bounds__(256) void k2_chain(
    float* __restrict__ Mstate, const float* __restrict__ ApowT)
{
    int idx = blockIdx.x * 256 + threadIdx.x;   // over BB*HH
    int b = idx >> 8, h = idx & 255;
    float aL = ApowT[127 * 256 + h];            // a^128
    float M = 0.0f;
#pragma unroll
    for (int c = 0; c < NC; ++c) {
        size_t o = ((size_t)b * NC + c) * HH + h;
        float prev = Mstate[o];
        Mstate[o] = M;                          // Minit for chunk c
        M = fmaf(aL, M, prev);
    }
}

// ---------------- K3: fixup + bias + sigmoid, 8 chunks/block ----------------
// grid = BB*4 = 256 blocks x 256 threads
__global__ __launch_bounds__(256) void k3_out(
    const float* __restrict__ ypart, const float* __restrict__ Mstate,
    const float* __restrict__ ApowT, const float* __restrict__ Wo,
    const float* __restrict__ bo, const float* __restrict__ ybias,
    float* __restrict__ out)
{
    __shared__ __align__(16) float wc[8 * 256];
    const int blk = blockIdx.x;
    const int b = blk >> 2, cg = blk & 3;       // chunks cg*8 .. cg*8+7
    const int tid = threadIdx.x;
#pragma unroll
    for (int cc = 0; cc < 8; ++cc)
        wc[cc * 256 + tid] =
            Wo[tid] * Mstate[((size_t)b * NC + cg * 8 + cc) * HH + tid];
    __syncthreads();

    const int k = tid & 127, hi = tid >> 7;     // hi: chunk group 0..1 -> 4 chunks each
    float corr[4] = {0.f, 0.f, 0.f, 0.f};
    const float* ap = &ApowT[k * 256];
#pragma unroll 4
    for (int h4 = 0; h4 < 64; ++h4) {
        float4 av = *reinterpret_cast<const float4*>(&ap[h4 * 4]);
#pragma unroll
        for (int c4 = 0; c4 < 4; ++c4) {
            float4 wv = *reinterpret_cast<const float4*>(&wc[(hi * 4 + c4) * 256 + h4 * 4]);
            corr[c4] += wv.x * av.x + wv.y * av.y + wv.z * av.z + wv.w * av.w;
        }
    }
    const float bk = ybias[k] + bo[0];
#pragma unroll
    for (int c4 = 0; c4 < 4; ++c4) {
        int c = cg * 8 + hi * 4 + c4;
        size_t t = (size_t)b * TT + (size_t)c * LC + k;
        float z = ypart[t] + corr[c4] + bk;
        out[t] = 1.0f / (1.0f + expf(-z));
    }
}

extern "C" void kernel_launch(void* const* d_in, const int* in_sizes, int n_in,
                              void* d_out, int out_size, void* d_ws, size_t ws_size,
                              hipStream_t stream) {
    const float* x   = (const float*)d_in[0];
    const float* Wd  = (const float*)d_in[1];
    const float* bd  = (const float*)d_in[2];
    const float* Wo  = (const float*)d_in[3];
    const float* bo  = (const float*)d_in[4];
    const float* tau = (const float*)d_in[5];
    float* out = (float*)d_out;

    float* ws = (float*)d_ws;
    float*  ypart  = ws;                          // 262144
    float*  Mstate = ws + 262144;                 // 524288
    float*  ApowT  = ws + 786432;                 // 32768: ApowT[k][h] = a_h^(k+1)
    float*  alphas = ws + 819200;                 // 256
    float*  mb     = ws + 819456;                 // 256
    float*  ybias  = ws + 819712;                 // 128
    ushort* Wdb    = (ushort*)(ws + 819840);      // 32768 u16
    ushort* Vt     = (ushort*)(ws + 836224);      // 32768 u16: Vt[d][h]

    k0_tables<<<128, 256, 0, stream>>>(Wd, bd, Wo, tau, Wdb, Vt, ApowT, alphas, mb, ybias);
    k1_fused<<<BB * NC, 512, 0, stream>>>(x, Wdb, Vt, alphas, mb, ApowT, ypart, Mstate);
    k2_chain<<<BB * HH / 256, 256, 0, stream>>>(Mstate, ApowT);
    k3_out<<<BB * 4, 256, 0, stream>>>(ypart, Mstate, ApowT, Wo, bo, ybias, out);
}